// Round 1
// baseline (633.987 us; speedup 1.0000x reference)
//
#include <hip/hip_runtime.h>
#include <hip/hip_bf16.h>

#define NEG_SLOPE 0.2f
#define BN_EPS 1e-5f

__device__ __forceinline__ float wred_sum(float v) {
    #pragma unroll
    for (int m = 32; m > 0; m >>= 1) v += __shfl_xor(v, m);
    return v;
}
__device__ __forceinline__ float wred_max(float v) {
    #pragma unroll
    for (int m = 32; m > 0; m >>= 1) v = fmaxf(v, __shfl_xor(v, m));
    return v;
}

// ---------------- CSR build ----------------
__global__ void hist_kernel(const int* __restrict__ ei, int E, int Et, int* __restrict__ deg) {
    int idx = blockIdx.x * blockDim.x + threadIdx.x;
    if (idx >= Et) return;
    int d = (idx < E) ? ei[E + idx] : (idx - E);   // dst row of edge_index, or self-loop
    atomicAdd(&deg[d], 1);
}

// single-block exclusive scan over deg[0..n) -> offs[0..n], offs[n] = total
__global__ void scan_kernel(const int* __restrict__ deg, int* __restrict__ offs, int n) {
    __shared__ int sums[1024];
    int tid = threadIdx.x;
    int chunk = (n + 1023) / 1024;
    int begin = tid * chunk;
    int end   = min(begin + chunk, n);
    int s = 0;
    for (int i = begin; i < end; ++i) s += deg[i];
    sums[tid] = s;
    __syncthreads();
    // Hillis-Steele inclusive scan
    for (int off = 1; off < 1024; off <<= 1) {
        int v = (tid >= off) ? sums[tid - off] : 0;
        __syncthreads();
        sums[tid] += v;
        __syncthreads();
    }
    int prefix = sums[tid] - s;   // exclusive prefix of this chunk
    for (int i = begin; i < end; ++i) { offs[i] = prefix; prefix += deg[i]; }
    if (tid == 1023) offs[n] = sums[1023];
}

__global__ void scatter_kernel(const int* __restrict__ ei, int E, int Et,
                               const int* __restrict__ offs, int* __restrict__ cur,
                               int* __restrict__ csr_src) {
    int idx = blockIdx.x * blockDim.x + threadIdx.x;
    if (idx >= Et) return;
    int s, d;
    if (idx < E) { s = ei[idx]; d = ei[E + idx]; }
    else         { s = idx - E; d = idx - E; }
    int pos = offs[d] + atomicAdd(&cur[d], 1);
    csr_src[pos] = s;
}

// ---------------- Layer 1 GEMM: h1 = x @ W1  (N x 128) @ (128 x 128) ----------------
__global__ __launch_bounds__(1024) void gemm1_kernel(const float* __restrict__ x,
                                                     const float* __restrict__ W,
                                                     float* __restrict__ h1, int Nn) {
    __shared__ float xs[8][128];
    int t = threadIdx.x;
    int row = t >> 7, col = t & 127;
    int n = blockIdx.x * 8 + row;
    if (n < Nn) xs[row][col] = x[n * 128 + col];
    __syncthreads();
    if (n >= Nn) return;
    float acc = 0.f;
    #pragma unroll
    for (int k = 0; k < 128; ++k) acc += xs[row][k] * W[k * 128 + col];
    h1[n * 128 + col] = acc;
}

// ---------------- per-node attention coefficients, layer 1 (heads=2, hid=64) ----------------
__global__ void al1_kernel(const float* __restrict__ h1,
                           const float* __restrict__ a1s, const float* __restrict__ a1d,
                           float* __restrict__ als, float* __restrict__ ald, int Nn) {
    int wid = threadIdx.x >> 6, lane = threadIdx.x & 63;
    int n = blockIdx.x * 4 + wid;
    if (n >= Nn) return;
    float v0 = h1[n * 128 + lane];
    float v1 = h1[n * 128 + 64 + lane];
    float s0 = wred_sum(v0 * a1s[lane]);
    float s1 = wred_sum(v1 * a1s[64 + lane]);
    float d0 = wred_sum(v0 * a1d[lane]);
    float d1 = wred_sum(v1 * a1d[64 + lane]);
    if (lane == 0) {
        als[n * 2] = s0; als[n * 2 + 1] = s1;
        ald[n * 2] = d0; ald[n * 2 + 1] = d1;
    }
}

// ---------------- per-node edge softmax (one wave per node), H heads ----------------
template <int H>
__global__ void edge_softmax_kernel(const int* __restrict__ offs, const int* __restrict__ csr,
                                    const float* __restrict__ als, const float* __restrict__ ald,
                                    float* __restrict__ lg, int Nn) {
    int wid = threadIdx.x >> 6, lane = threadIdx.x & 63;
    int n = blockIdx.x * 4 + wid;
    if (n >= Nn) return;
    int b = offs[n], e = offs[n + 1];
    float aldn[H];
    #pragma unroll
    for (int h = 0; h < H; ++h) aldn[h] = ald[n * H + h];
    float mx[H];
    #pragma unroll
    for (int h = 0; h < H; ++h) mx[h] = -1e30f;
    for (int p = b + lane; p < e; p += 64) {
        int s = csr[p];
        #pragma unroll
        for (int h = 0; h < H; ++h) {
            float l = als[s * H + h] + aldn[h];
            l = (l > 0.f) ? l : NEG_SLOPE * l;
            lg[p * H + h] = l;
            mx[h] = fmaxf(mx[h], l);
        }
    }
    #pragma unroll
    for (int h = 0; h < H; ++h) mx[h] = wred_max(mx[h]);
    float sm[H];
    #pragma unroll
    for (int h = 0; h < H; ++h) sm[h] = 0.f;
    for (int p = b + lane; p < e; p += 64) {
        #pragma unroll
        for (int h = 0; h < H; ++h) sm[h] += expf(lg[p * H + h] - mx[h]);
    }
    float inv[H];
    #pragma unroll
    for (int h = 0; h < H; ++h) { sm[h] = wred_sum(sm[h]); inv[h] = 1.f / (sm[h] + 1e-16f); }
    for (int p = b + lane; p < e; p += 64) {
        #pragma unroll
        for (int h = 0; h < H; ++h) lg[p * H + h] = expf(lg[p * H + h] - mx[h]) * inv[h];
    }
}

// ---------------- layer-1 aggregation + bias + BN(eval) + ReLU ----------------
__global__ void agg1_kernel(const int* __restrict__ offs, const int* __restrict__ csr,
                            const float* __restrict__ h1, const float* __restrict__ alpha,
                            const float* __restrict__ b1, const float* __restrict__ gam,
                            const float* __restrict__ bet, const float* __restrict__ mean,
                            const float* __restrict__ var, float* __restrict__ hbn, int Nn) {
    int n = blockIdx.x;
    int c = threadIdx.x;           // 0..127
    int h = c >> 6;
    int b = offs[n], e = offs[n + 1];
    float acc = 0.f;
    for (int p = b; p < e; ++p) {
        int s = csr[p];
        float a = alpha[p * 2 + h];
        acc += h1[s * 128 + c] * a;
    }
    float v = acc + b1[c];
    v = (v - mean[c]) * rsqrtf(var[c] + BN_EPS) * gam[c] + bet[c];
    hbn[n * 128 + c] = fmaxf(v, 0.f);
}

// ---------------- layer 2 GEMM (N x 128)@(128 x 40) + attention coeffs ----------------
__global__ void gemm2_al2_kernel(const float* __restrict__ hbn, const float* __restrict__ W2,
                                 const float* __restrict__ a2s, const float* __restrict__ a2d,
                                 float* __restrict__ h2, float* __restrict__ als,
                                 float* __restrict__ ald, int Nn) {
    int wid = threadIdx.x >> 6, lane = threadIdx.x & 63;
    int n = blockIdx.x * 4 + wid;
    if (n >= Nn) return;
    float acc = 0.f;
    if (lane < 40) {
        const float* xr = hbn + n * 128;
        #pragma unroll
        for (int k = 0; k < 128; ++k) acc += xr[k] * W2[k * 40 + lane];
    }
    float s = wred_sum(lane < 40 ? acc * a2s[lane] : 0.f);
    float d = wred_sum(lane < 40 ? acc * a2d[lane] : 0.f);
    if (lane < 40) h2[n * 40 + lane] = acc;
    if (lane == 0) { als[n] = s; ald[n] = d; }
}

// ---------------- layer-2 aggregation + bias + log_softmax ----------------
__global__ void agg2_lsm_kernel(const int* __restrict__ offs, const int* __restrict__ csr,
                                const float* __restrict__ h2, const float* __restrict__ alpha,
                                const float* __restrict__ b2, float* __restrict__ out, int Nn) {
    int n = blockIdx.x;
    int lane = threadIdx.x;        // 0..63 (one wave)
    int b = offs[n], e = offs[n + 1];
    float acc = 0.f;
    for (int p = b; p < e; ++p) {
        float a = alpha[p];
        int s = csr[p];
        if (lane < 40) acc += h2[s * 40 + lane] * a;
    }
    float v = (lane < 40) ? (acc + b2[lane]) : -1e30f;
    float m = wred_max(v);
    float ex = (lane < 40) ? expf(v - m) : 0.f;
    float ssum = wred_sum(ex);
    if (lane < 40) out[n * 40 + lane] = v - m - logf(ssum);
}

extern "C" void kernel_launch(void* const* d_in, const int* in_sizes, int n_in,
                              void* d_out, int out_size, void* d_ws, size_t ws_size,
                              hipStream_t stream) {
    const float* x    = (const float*)d_in[0];
    const int*   ei   = (const int*)d_in[1];
    const float* W1   = (const float*)d_in[2];
    const float* a1s  = (const float*)d_in[3];
    const float* a1d  = (const float*)d_in[4];
    const float* b1   = (const float*)d_in[5];
    const float* g1   = (const float*)d_in[6];
    const float* be1  = (const float*)d_in[7];
    const float* mn1  = (const float*)d_in[8];
    const float* vr1  = (const float*)d_in[9];
    const float* W2   = (const float*)d_in[10];
    const float* a2s  = (const float*)d_in[11];
    const float* a2d  = (const float*)d_in[12];
    const float* b2   = (const float*)d_in[13];
    float* out = (float*)d_out;

    const int N  = in_sizes[0] / 128;
    const int E  = in_sizes[1] / 2;
    const int Et = E + N;

    // workspace carve (256B aligned)
    char* p = (char*)d_ws;
    auto alloc = [&](size_t bytes) -> void* {
        void* r = (void*)p;
        p += (bytes + 255) & ~(size_t)255;
        return r;
    };
    int*   deg   = (int*)alloc((size_t)N * 4);
    int*   offs  = (int*)alloc((size_t)(N + 1) * 4);
    int*   cur   = (int*)alloc((size_t)N * 4);
    int*   csr   = (int*)alloc((size_t)Et * 4);
    float* h1    = (float*)alloc((size_t)N * 128 * 4);
    float* al1sv = (float*)alloc((size_t)N * 2 * 4);
    float* al1dv = (float*)alloc((size_t)N * 2 * 4);
    float* lg1   = (float*)alloc((size_t)Et * 2 * 4);
    float* hbn   = (float*)alloc((size_t)N * 128 * 4);
    float* h2    = (float*)alloc((size_t)N * 40 * 4);
    float* al2sv = (float*)alloc((size_t)N * 4);
    float* al2dv = (float*)alloc((size_t)N * 4);
    float* lg2   = (float*)alloc((size_t)Et * 4);
    (void)ws_size;

    hipMemsetAsync(deg, 0, (size_t)N * 4, stream);
    hipMemsetAsync(cur, 0, (size_t)N * 4, stream);

    int tpb = 256;
    hist_kernel<<<(Et + tpb - 1) / tpb, tpb, 0, stream>>>(ei, E, Et, deg);
    scan_kernel<<<1, 1024, 0, stream>>>(deg, offs, N);
    scatter_kernel<<<(Et + tpb - 1) / tpb, tpb, 0, stream>>>(ei, E, Et, offs, cur, csr);

    gemm1_kernel<<<(N + 7) / 8, 1024, 0, stream>>>(x, W1, h1, N);
    al1_kernel<<<(N + 3) / 4, 256, 0, stream>>>(h1, a1s, a1d, al1sv, al1dv, N);
    edge_softmax_kernel<2><<<(N + 3) / 4, 256, 0, stream>>>(offs, csr, al1sv, al1dv, lg1, N);
    agg1_kernel<<<N, 128, 0, stream>>>(offs, csr, h1, lg1, b1, g1, be1, mn1, vr1, hbn, N);

    gemm2_al2_kernel<<<(N + 3) / 4, 256, 0, stream>>>(hbn, W2, a2s, a2d, h2, al2sv, al2dv, N);
    edge_softmax_kernel<1><<<(N + 3) / 4, 256, 0, stream>>>(offs, csr, al2sv, al2dv, lg2, N);
    agg2_lsm_kernel<<<N, 64, 0, stream>>>(offs, csr, h2, lg2, b2, out, N);
}

// Round 2
// 474.237 us; speedup vs baseline: 1.3369x; 1.3369x over previous
//
#include <hip/hip_runtime.h>
#include <hip/hip_bf16.h>

#define NEG_SLOPE 0.2f
#define BN_EPS 1e-5f

__device__ __forceinline__ float wred_sum(float v) {
    #pragma unroll
    for (int m = 32; m > 0; m >>= 1) v += __shfl_xor(v, m);
    return v;
}
__device__ __forceinline__ float wred_max(float v) {
    #pragma unroll
    for (int m = 32; m > 0; m >>= 1) v = fmaxf(v, __shfl_xor(v, m));
    return v;
}

// ---------------- CSR build ----------------
__global__ void hist_kernel(const int* __restrict__ ei, int E, int Et, int* __restrict__ deg) {
    int idx = blockIdx.x * blockDim.x + threadIdx.x;
    if (idx >= Et) return;
    int d = (idx < E) ? ei[E + idx] : (idx - E);
    atomicAdd(&deg[d], 1);
}

__global__ void scan_kernel(const int* __restrict__ deg, int* __restrict__ offs, int n) {
    __shared__ int sums[1024];
    int tid = threadIdx.x;
    int chunk = (n + 1023) / 1024;
    int begin = tid * chunk;
    int end   = min(begin + chunk, n);
    int s = 0;
    for (int i = begin; i < end; ++i) s += deg[i];
    sums[tid] = s;
    __syncthreads();
    for (int off = 1; off < 1024; off <<= 1) {
        int v = (tid >= off) ? sums[tid - off] : 0;
        __syncthreads();
        sums[tid] += v;
        __syncthreads();
    }
    int prefix = sums[tid] - s;
    for (int i = begin; i < end; ++i) { offs[i] = prefix; prefix += deg[i]; }
    if (tid == 1023) offs[n] = sums[1023];
}

__global__ void scatter_kernel(const int* __restrict__ ei, int E, int Et,
                               const int* __restrict__ offs, int* __restrict__ cur,
                               int* __restrict__ csr_src) {
    int idx = blockIdx.x * blockDim.x + threadIdx.x;
    if (idx >= Et) return;
    int s, d;
    if (idx < E) { s = ei[idx]; d = ei[E + idx]; }
    else         { s = idx - E; d = idx - E; }
    int pos = offs[d] + atomicAdd(&cur[d], 1);
    csr_src[pos] = s;
}

// ---------------- Layer 1 GEMM: h1 = x @ W1, (N x 128)@(128 x 128), tiled ----------------
// Block 256 threads, tile 64 rows x 128 cols, BK=32, micro-tile 4 rows x 8 cols.
__global__ __launch_bounds__(256) void gemm1_tiled(const float* __restrict__ x,
                                                   const float* __restrict__ W,
                                                   float* __restrict__ h1, int Nn) {
    __shared__ float As[64][33];    // [row][k] pad 33 -> 2-way max
    __shared__ float Bs[32][132];   // [k][col] pad 132 -> 2-way reads
    int t  = threadIdx.x;
    int tx = t & 15;                // col group: cols 4tx..4tx+3 and 64+4tx..
    int ty = t >> 4;                // row group: rows 4ty..4ty+3
    int br = blockIdx.x * 64;

    float acc[4][8];
    #pragma unroll
    for (int i = 0; i < 4; ++i)
        #pragma unroll
        for (int j = 0; j < 8; ++j) acc[i][j] = 0.f;

    int k4  = t & 7;                // A-load mapping
    int rowA = t >> 3;              // 0..31

    for (int k0 = 0; k0 < 128; k0 += 32) {
        #pragma unroll
        for (int i = 0; i < 2; ++i) {
            int r  = rowA + 32 * i;
            int gr = min(br + r, Nn - 1);
            float4 v = *(const float4*)(x + (size_t)gr * 128 + k0 + 4 * k4);
            As[r][4 * k4 + 0] = v.x; As[r][4 * k4 + 1] = v.y;
            As[r][4 * k4 + 2] = v.z; As[r][4 * k4 + 3] = v.w;
        }
        #pragma unroll
        for (int i = 0; i < 4; ++i) {
            int f  = t + 256 * i;
            int kk = f >> 5, c4 = f & 31;
            *(float4*)&Bs[kk][4 * c4] = *(const float4*)(W + (size_t)(k0 + kk) * 128 + 4 * c4);
        }
        __syncthreads();
        #pragma unroll
        for (int kk = 0; kk < 32; ++kk) {
            float4 b0 = *(const float4*)&Bs[kk][4 * tx];
            float4 b1 = *(const float4*)&Bs[kk][64 + 4 * tx];
            #pragma unroll
            for (int i = 0; i < 4; ++i) {
                float a = As[4 * ty + i][kk];
                acc[i][0] += a * b0.x; acc[i][1] += a * b0.y;
                acc[i][2] += a * b0.z; acc[i][3] += a * b0.w;
                acc[i][4] += a * b1.x; acc[i][5] += a * b1.y;
                acc[i][6] += a * b1.z; acc[i][7] += a * b1.w;
            }
        }
        __syncthreads();
    }
    #pragma unroll
    for (int i = 0; i < 4; ++i) {
        int r = br + 4 * ty + i;
        if (r < Nn) {
            float4 o0 = {acc[i][0], acc[i][1], acc[i][2], acc[i][3]};
            float4 o1 = {acc[i][4], acc[i][5], acc[i][6], acc[i][7]};
            *(float4*)(h1 + (size_t)r * 128 + 4 * tx)      = o0;
            *(float4*)(h1 + (size_t)r * 128 + 64 + 4 * tx) = o1;
        }
    }
}

// ---------------- per-node attention coefficients, layer 1 ----------------
__global__ void al1_kernel(const float* __restrict__ h1,
                           const float* __restrict__ a1s, const float* __restrict__ a1d,
                           float* __restrict__ als, float* __restrict__ ald, int Nn) {
    int wid = threadIdx.x >> 6, lane = threadIdx.x & 63;
    int n = blockIdx.x * 4 + wid;
    if (n >= Nn) return;
    float v0 = h1[n * 128 + lane];
    float v1 = h1[n * 128 + 64 + lane];
    float s0 = wred_sum(v0 * a1s[lane]);
    float s1 = wred_sum(v1 * a1s[64 + lane]);
    float d0 = wred_sum(v0 * a1d[lane]);
    float d1 = wred_sum(v1 * a1d[64 + lane]);
    if (lane == 0) {
        als[n * 2] = s0; als[n * 2 + 1] = s1;
        ald[n * 2] = d0; ald[n * 2 + 1] = d1;
    }
}

// ---------------- per-node edge softmax, 2-pass: store unnormalized exp + 1/s ----------------
template <int H>
__global__ void edge_softmax_kernel(const int* __restrict__ offs, const int* __restrict__ csr,
                                    const float* __restrict__ als, const float* __restrict__ ald,
                                    float* __restrict__ lg, float* __restrict__ invs, int Nn) {
    int wid = threadIdx.x >> 6, lane = threadIdx.x & 63;
    int n = blockIdx.x * 4 + wid;
    if (n >= Nn) return;
    int b = offs[n], e = offs[n + 1];
    float aldn[H];
    #pragma unroll
    for (int h = 0; h < H; ++h) aldn[h] = ald[n * H + h];
    float mx[H];
    #pragma unroll
    for (int h = 0; h < H; ++h) mx[h] = -1e30f;
    for (int p = b + lane; p < e; p += 64) {
        int s = csr[p];
        #pragma unroll
        for (int h = 0; h < H; ++h) {
            float l = als[s * H + h] + aldn[h];
            l = (l > 0.f) ? l : NEG_SLOPE * l;
            lg[p * H + h] = l;
            mx[h] = fmaxf(mx[h], l);
        }
    }
    #pragma unroll
    for (int h = 0; h < H; ++h) mx[h] = wred_max(mx[h]);
    float sm[H];
    #pragma unroll
    for (int h = 0; h < H; ++h) sm[h] = 0.f;
    for (int p = b + lane; p < e; p += 64) {
        #pragma unroll
        for (int h = 0; h < H; ++h) {
            float t = expf(lg[p * H + h] - mx[h]);
            lg[p * H + h] = t;
            sm[h] += t;
        }
    }
    #pragma unroll
    for (int h = 0; h < H; ++h) sm[h] = wred_sum(sm[h]);
    if (lane == 0) {
        #pragma unroll
        for (int h = 0; h < H; ++h) invs[n * H + h] = 1.f / (sm[h] + 1e-16f);
    }
}

// ---------------- layer-1 aggregation (wave/node, float4, 2 edges/iter) + bias+BN+ReLU ----------------
__global__ __launch_bounds__(256) void agg1_kernel(const int* __restrict__ offs, const int* __restrict__ csr,
                            const float* __restrict__ h1, const float* __restrict__ ex,
                            const float* __restrict__ invs,
                            const float* __restrict__ b1, const float* __restrict__ gam,
                            const float* __restrict__ bet, const float* __restrict__ mean,
                            const float* __restrict__ var, float* __restrict__ hbn, int Nn) {
    int wid = threadIdx.x >> 6, lane = threadIdx.x & 63;
    int n = blockIdx.x * 4 + wid;
    if (n >= Nn) return;
    int sub = lane >> 5, l32 = lane & 31;
    int head = l32 >> 4;
    int b = offs[n], e = offs[n + 1];
    float4 acc = {0.f, 0.f, 0.f, 0.f};
    for (int p = b + sub; p < e; p += 2) {
        int s = csr[p];
        float a = ex[p * 2 + head];
        float4 v = *(const float4*)(h1 + (size_t)s * 128 + 4 * l32);
        acc.x += v.x * a; acc.y += v.y * a; acc.z += v.z * a; acc.w += v.w * a;
    }
    acc.x += __shfl_xor(acc.x, 32);
    acc.y += __shfl_xor(acc.y, 32);
    acc.z += __shfl_xor(acc.z, 32);
    acc.w += __shfl_xor(acc.w, 32);
    if (sub == 0) {
        float inv = invs[n * 2 + head];
        int c = 4 * l32;
        float4 bb = *(const float4*)(b1 + c);
        float4 gg = *(const float4*)(gam + c);
        float4 be = *(const float4*)(bet + c);
        float4 mm = *(const float4*)(mean + c);
        float4 vv = *(const float4*)(var + c);
        float4 o;
        o.x = fmaxf((acc.x * inv + bb.x - mm.x) * rsqrtf(vv.x + BN_EPS) * gg.x + be.x, 0.f);
        o.y = fmaxf((acc.y * inv + bb.y - mm.y) * rsqrtf(vv.y + BN_EPS) * gg.y + be.y, 0.f);
        o.z = fmaxf((acc.z * inv + bb.z - mm.z) * rsqrtf(vv.z + BN_EPS) * gg.z + be.z, 0.f);
        o.w = fmaxf((acc.w * inv + bb.w - mm.w) * rsqrtf(vv.w + BN_EPS) * gg.w + be.w, 0.f);
        *(float4*)(hbn + (size_t)n * 128 + c) = o;
    }
}

// ---------------- layer 2 GEMM tiled: h2p = hbn @ W2pad (N x 128)@(128 x 64-pad), + al2 fused ----------------
__global__ __launch_bounds__(256) void gemm2_tiled(const float* __restrict__ hbn,
                                                   const float* __restrict__ W2,
                                                   const float* __restrict__ a2s,
                                                   const float* __restrict__ a2d,
                                                   float* __restrict__ h2p,
                                                   float* __restrict__ als, float* __restrict__ ald,
                                                   int Nn) {
    __shared__ float As[64][33];
    __shared__ float Bs[128][68];   // [k][col] padded cols 64 (40..63 zero), stride 68
    __shared__ float redS[64][17];
    __shared__ float redD[64][17];
    int t  = threadIdx.x;
    int tx = t & 15;                // cols 4tx..4tx+3
    int ty = t >> 4;                // rows 4ty..4ty+3
    int br = blockIdx.x * 64;

    // stage W2 (padded) once: 128x64 -> 2048 float4, 8 per thread
    #pragma unroll
    for (int i = 0; i < 8; ++i) {
        int f  = t + 256 * i;
        int kk = f >> 4, c4 = f & 15;
        float4 v = {0.f, 0.f, 0.f, 0.f};
        if (c4 < 10) v = *(const float4*)(W2 + (size_t)kk * 40 + 4 * c4);
        *(float4*)&Bs[kk][4 * c4] = v;
    }
    float as4[4], ad4[4];
    #pragma unroll
    for (int j = 0; j < 4; ++j) {
        int c = 4 * tx + j;
        as4[j] = (c < 40) ? a2s[c] : 0.f;
        ad4[j] = (c < 40) ? a2d[c] : 0.f;
    }

    float acc[4][4];
    #pragma unroll
    for (int i = 0; i < 4; ++i)
        #pragma unroll
        for (int j = 0; j < 4; ++j) acc[i][j] = 0.f;

    int k4  = t & 7;
    int rowA = t >> 3;
    __syncthreads();

    for (int k0 = 0; k0 < 128; k0 += 32) {
        #pragma unroll
        for (int i = 0; i < 2; ++i) {
            int r  = rowA + 32 * i;
            int gr = min(br + r, Nn - 1);
            float4 v = *(const float4*)(hbn + (size_t)gr * 128 + k0 + 4 * k4);
            As[r][4 * k4 + 0] = v.x; As[r][4 * k4 + 1] = v.y;
            As[r][4 * k4 + 2] = v.z; As[r][4 * k4 + 3] = v.w;
        }
        __syncthreads();
        #pragma unroll
        for (int kk = 0; kk < 32; ++kk) {
            float4 b0 = *(const float4*)&Bs[k0 + kk][4 * tx];
            #pragma unroll
            for (int i = 0; i < 4; ++i) {
                float a = As[4 * ty + i][kk];
                acc[i][0] += a * b0.x; acc[i][1] += a * b0.y;
                acc[i][2] += a * b0.z; acc[i][3] += a * b0.w;
            }
        }
        __syncthreads();
    }
    // store h2p + fused al2 partials
    float pS[4], pD[4];
    #pragma unroll
    for (int i = 0; i < 4; ++i) {
        pS[i] = acc[i][0] * as4[0] + acc[i][1] * as4[1] + acc[i][2] * as4[2] + acc[i][3] * as4[3];
        pD[i] = acc[i][0] * ad4[0] + acc[i][1] * ad4[1] + acc[i][2] * ad4[2] + acc[i][3] * ad4[3];
        redS[4 * ty + i][tx] = pS[i];
        redD[4 * ty + i][tx] = pD[i];
        int r = br + 4 * ty + i;
        if (r < Nn) {
            float4 o = {acc[i][0], acc[i][1], acc[i][2], acc[i][3]};
            *(float4*)(h2p + (size_t)r * 64 + 4 * tx) = o;
        }
    }
    __syncthreads();
    if (t < 64) {
        int r = br + t;
        if (r < Nn) {
            float sS = 0.f, sD = 0.f;
            #pragma unroll
            for (int xx = 0; xx < 16; ++xx) { sS += redS[t][xx]; sD += redD[t][xx]; }
            als[r] = sS; ald[r] = sD;
        }
    }
}

// ---------------- layer-2 aggregation (wave/node, float2 on 64-pad) + bias + log_softmax ----------------
__global__ __launch_bounds__(256) void agg2_kernel(const int* __restrict__ offs, const int* __restrict__ csr,
                            const float* __restrict__ h2p, const float* __restrict__ ex,
                            const float* __restrict__ invs, const float* __restrict__ b2,
                            float* __restrict__ out, int Nn) {
    int wid = threadIdx.x >> 6, lane = threadIdx.x & 63;
    int n = blockIdx.x * 4 + wid;
    if (n >= Nn) return;
    int sub = lane >> 5, l32 = lane & 31;
    int b = offs[n], e = offs[n + 1];
    float2 acc = {0.f, 0.f};
    for (int p = b + sub; p < e; p += 2) {
        int s = csr[p];
        float a = ex[p];
        float2 v = *(const float2*)(h2p + (size_t)s * 64 + 2 * l32);
        acc.x += v.x * a; acc.y += v.y * a;
    }
    acc.x += __shfl_xor(acc.x, 32);
    acc.y += __shfl_xor(acc.y, 32);
    float inv = invs[n];
    bool valid = (sub == 0) && (l32 < 20);
    float v0 = -1e30f, v1 = -1e30f;
    if (valid) {
        v0 = acc.x * inv + b2[2 * l32];
        v1 = acc.y * inv + b2[2 * l32 + 1];
    }
    float m = wred_max(fmaxf(v0, v1));
    float es = valid ? (expf(v0 - m) + expf(v1 - m)) : 0.f;
    float ssum = wred_sum(es);
    float lse = m + logf(ssum);
    if (valid) {
        float2 o = {v0 - lse, v1 - lse};
        *(float2*)(out + (size_t)n * 40 + 2 * l32) = o;
    }
}

extern "C" void kernel_launch(void* const* d_in, const int* in_sizes, int n_in,
                              void* d_out, int out_size, void* d_ws, size_t ws_size,
                              hipStream_t stream) {
    const float* x    = (const float*)d_in[0];
    const int*   ei   = (const int*)d_in[1];
    const float* W1   = (const float*)d_in[2];
    const float* a1s  = (const float*)d_in[3];
    const float* a1d  = (const float*)d_in[4];
    const float* b1   = (const float*)d_in[5];
    const float* g1   = (const float*)d_in[6];
    const float* be1  = (const float*)d_in[7];
    const float* mn1  = (const float*)d_in[8];
    const float* vr1  = (const float*)d_in[9];
    const float* W2   = (const float*)d_in[10];
    const float* a2s  = (const float*)d_in[11];
    const float* a2d  = (const float*)d_in[12];
    const float* b2   = (const float*)d_in[13];
    float* out = (float*)d_out;

    const int N  = in_sizes[0] / 128;
    const int E  = in_sizes[1] / 2;
    const int Et = E + N;

    char* p = (char*)d_ws;
    auto alloc = [&](size_t bytes) -> void* {
        void* r = (void*)p;
        p += (bytes + 255) & ~(size_t)255;
        return r;
    };
    int*   deg   = (int*)alloc((size_t)N * 4);
    int*   offs  = (int*)alloc((size_t)(N + 1) * 4);
    int*   cur   = (int*)alloc((size_t)N * 4);
    int*   csr   = (int*)alloc((size_t)Et * 4);
    float* h1    = (float*)alloc((size_t)N * 128 * 4);
    float* al1sv = (float*)alloc((size_t)N * 2 * 4);
    float* al1dv = (float*)alloc((size_t)N * 2 * 4);
    float* ex1   = (float*)alloc((size_t)Et * 2 * 4);
    float* inv1  = (float*)alloc((size_t)N * 2 * 4);
    float* hbn   = (float*)alloc((size_t)N * 128 * 4);
    float* h2p   = (float*)alloc((size_t)N * 64 * 4);
    float* al2sv = (float*)alloc((size_t)N * 4);
    float* al2dv = (float*)alloc((size_t)N * 4);
    float* ex2   = (float*)alloc((size_t)Et * 4);
    float* inv2  = (float*)alloc((size_t)N * 4);
    (void)ws_size;

    hipMemsetAsync(deg, 0, (size_t)N * 4, stream);
    hipMemsetAsync(cur, 0, (size_t)N * 4, stream);

    int tpb = 256;
    hist_kernel<<<(Et + tpb - 1) / tpb, tpb, 0, stream>>>(ei, E, Et, deg);
    scan_kernel<<<1, 1024, 0, stream>>>(deg, offs, N);
    scatter_kernel<<<(Et + tpb - 1) / tpb, tpb, 0, stream>>>(ei, E, Et, offs, cur, csr);

    gemm1_tiled<<<(N + 63) / 64, 256, 0, stream>>>(x, W1, h1, N);
    al1_kernel<<<(N + 3) / 4, 256, 0, stream>>>(h1, a1s, a1d, al1sv, al1dv, N);
    edge_softmax_kernel<2><<<(N + 3) / 4, 256, 0, stream>>>(offs, csr, al1sv, al1dv, ex1, inv1, N);
    agg1_kernel<<<(N + 3) / 4, 256, 0, stream>>>(offs, csr, h1, ex1, inv1, b1, g1, be1, mn1, vr1, hbn, N);

    gemm2_tiled<<<(N + 63) / 64, 256, 0, stream>>>(hbn, W2, a2s, a2d, h2p, al2sv, al2dv, N);
    edge_softmax_kernel<1><<<(N + 3) / 4, 256, 0, stream>>>(offs, csr, al2sv, al2dv, ex2, inv2, N);
    agg2_kernel<<<(N + 3) / 4, 256, 0, stream>>>(offs, csr, h2p, ex2, inv2, b2, out, N);
}

// Round 3
// 397.721 us; speedup vs baseline: 1.5940x; 1.1924x over previous
//
#include <hip/hip_runtime.h>
#include <hip/hip_bf16.h>

#define NEG_SLOPE 0.2f
#define BN_EPS 1e-5f

__device__ __forceinline__ float wred_sum(float v) {
    #pragma unroll
    for (int m = 32; m > 0; m >>= 1) v += __shfl_xor(v, m);
    return v;
}
__device__ __forceinline__ float wred_max(float v) {
    #pragma unroll
    for (int m = 32; m > 0; m >>= 1) v = fmaxf(v, __shfl_xor(v, m));
    return v;
}

// ---------------- CSR build ----------------
__global__ void hist_kernel(const int* __restrict__ ei, int E, int Et, int* __restrict__ deg) {
    int idx = blockIdx.x * blockDim.x + threadIdx.x;
    if (idx >= Et) return;
    int d = (idx < E) ? ei[E + idx] : (idx - E);
    atomicAdd(&deg[d], 1);
}

// --- 3-phase multi-block exclusive scan: deg[0..n) -> offs[0..n] (+ cur = copy) ---
#define SCAN_CHUNK 2048

__global__ __launch_bounds__(256) void scan_blocksum(const int* __restrict__ deg,
                                                     int* __restrict__ bsum, int n) {
    __shared__ int red[256];
    int b = blockIdx.x, t = threadIdx.x;
    int base = b * SCAN_CHUNK + t * 8;
    int s = 0;
    #pragma unroll
    for (int i = 0; i < 8; ++i) { int idx = base + i; if (idx < n) s += deg[idx]; }
    red[t] = s;
    __syncthreads();
    for (int off = 128; off > 0; off >>= 1) {
        if (t < off) red[t] += red[t + off];
        __syncthreads();
    }
    if (t == 0) bsum[b] = red[0];
}

__global__ __launch_bounds__(1024) void scan_bsums(const int* __restrict__ bsum,
                                                   int* __restrict__ bpre, int nb) {
    __shared__ int s[1024];
    int t = threadIdx.x;
    int v = (t < nb) ? bsum[t] : 0;
    s[t] = v;
    __syncthreads();
    for (int off = 1; off < 1024; off <<= 1) {
        int u = (t >= off) ? s[t - off] : 0;
        __syncthreads();
        s[t] += u;
        __syncthreads();
    }
    if (t < nb) bpre[t] = s[t] - v;       // exclusive prefix per block
    if (t == 1023) bpre[nb] = s[1023];    // grand total
}

__global__ __launch_bounds__(256) void scan_scatter(const int* __restrict__ deg,
                                                    const int* __restrict__ bpre,
                                                    int* __restrict__ offs, int* __restrict__ cur,
                                                    int n, int nb) {
    __shared__ int red[256];
    int b = blockIdx.x, t = threadIdx.x;
    int base = b * SCAN_CHUNK + t * 8;
    int loc[8];
    int s = 0;
    #pragma unroll
    for (int i = 0; i < 8; ++i) {
        int idx = base + i;
        int d = (idx < n) ? deg[idx] : 0;
        loc[i] = s;
        s += d;
    }
    red[t] = s;
    __syncthreads();
    int v = s;
    for (int off = 1; off < 256; off <<= 1) {
        int u = (t >= off) ? red[t - off] : 0;
        __syncthreads();
        red[t] += u;
        __syncthreads();
    }
    int tpre = red[t] - v + bpre[b];
    #pragma unroll
    for (int i = 0; i < 8; ++i) {
        int idx = base + i;
        if (idx < n) {
            int o = tpre + loc[i];
            offs[idx] = o;
            cur[idx]  = o;
        }
    }
    if (b == 0 && t == 0) offs[n] = bpre[nb];
}

__global__ void scatter_kernel(const int* __restrict__ ei, int E, int Et,
                               int* __restrict__ cur, int* __restrict__ csr_src) {
    int idx = blockIdx.x * blockDim.x + threadIdx.x;
    if (idx >= Et) return;
    int s, d;
    if (idx < E) { s = ei[idx]; d = ei[E + idx]; }
    else         { s = idx - E; d = idx - E; }
    int pos = atomicAdd(&cur[d], 1);
    csr_src[pos] = s;
}

// ---------------- Layer 1 GEMM + fused al1: h1 = x @ W1, (N x 128)@(128 x 128) ----------------
__global__ __launch_bounds__(256) void gemm1_tiled(const float* __restrict__ x,
                                                   const float* __restrict__ W,
                                                   const float* __restrict__ a1s,
                                                   const float* __restrict__ a1d,
                                                   float* __restrict__ h1,
                                                   float* __restrict__ als,
                                                   float* __restrict__ ald, int Nn) {
    __shared__ float As[64][33];
    __shared__ float Bs[32][132];
    __shared__ float4 red4[64][17];   // {s0,s1,d0,d1} partials per row per col-group
    int t  = threadIdx.x;
    int tx = t & 15;
    int ty = t >> 4;
    int br = blockIdx.x * 64;

    float acc[4][8];
    #pragma unroll
    for (int i = 0; i < 4; ++i)
        #pragma unroll
        for (int j = 0; j < 8; ++j) acc[i][j] = 0.f;

    int k4  = t & 7;
    int rowA = t >> 3;

    for (int k0 = 0; k0 < 128; k0 += 32) {
        #pragma unroll
        for (int i = 0; i < 2; ++i) {
            int r  = rowA + 32 * i;
            int gr = min(br + r, Nn - 1);
            float4 v = *(const float4*)(x + (size_t)gr * 128 + k0 + 4 * k4);
            As[r][4 * k4 + 0] = v.x; As[r][4 * k4 + 1] = v.y;
            As[r][4 * k4 + 2] = v.z; As[r][4 * k4 + 3] = v.w;
        }
        #pragma unroll
        for (int i = 0; i < 4; ++i) {
            int f  = t + 256 * i;
            int kk = f >> 5, c4 = f & 31;
            *(float4*)&Bs[kk][4 * c4] = *(const float4*)(W + (size_t)(k0 + kk) * 128 + 4 * c4);
        }
        __syncthreads();
        #pragma unroll
        for (int kk = 0; kk < 32; ++kk) {
            float4 b0 = *(const float4*)&Bs[kk][4 * tx];
            float4 b1 = *(const float4*)&Bs[kk][64 + 4 * tx];
            #pragma unroll
            for (int i = 0; i < 4; ++i) {
                float a = As[4 * ty + i][kk];
                acc[i][0] += a * b0.x; acc[i][1] += a * b0.y;
                acc[i][2] += a * b0.z; acc[i][3] += a * b0.w;
                acc[i][4] += a * b1.x; acc[i][5] += a * b1.y;
                acc[i][6] += a * b1.z; acc[i][7] += a * b1.w;
            }
        }
        __syncthreads();
    }
    // attention-coefficient vectors for this thread's 8 columns
    float s_lo[4], s_hi[4], d_lo[4], d_hi[4];
    #pragma unroll
    for (int j = 0; j < 4; ++j) {
        s_lo[j] = a1s[4 * tx + j];      s_hi[j] = a1s[64 + 4 * tx + j];
        d_lo[j] = a1d[4 * tx + j];      d_hi[j] = a1d[64 + 4 * tx + j];
    }
    #pragma unroll
    for (int i = 0; i < 4; ++i) {
        float4 pp = {0.f, 0.f, 0.f, 0.f};
        #pragma unroll
        for (int j = 0; j < 4; ++j) {
            pp.x += acc[i][j] * s_lo[j];
            pp.y += acc[i][4 + j] * s_hi[j];
            pp.z += acc[i][j] * d_lo[j];
            pp.w += acc[i][4 + j] * d_hi[j];
        }
        red4[4 * ty + i][tx] = pp;
        int r = br + 4 * ty + i;
        if (r < Nn) {
            float4 o0 = {acc[i][0], acc[i][1], acc[i][2], acc[i][3]};
            float4 o1 = {acc[i][4], acc[i][5], acc[i][6], acc[i][7]};
            *(float4*)(h1 + (size_t)r * 128 + 4 * tx)      = o0;
            *(float4*)(h1 + (size_t)r * 128 + 64 + 4 * tx) = o1;
        }
    }
    __syncthreads();
    if (t < 64) {
        int r = br + t;
        if (r < Nn) {
            float4 s = {0.f, 0.f, 0.f, 0.f};
            #pragma unroll
            for (int xx = 0; xx < 16; ++xx) {
                float4 p = red4[t][xx];
                s.x += p.x; s.y += p.y; s.z += p.z; s.w += p.w;
            }
            als[r * 2] = s.x; als[r * 2 + 1] = s.y;
            ald[r * 2] = s.z; ald[r * 2 + 1] = s.w;
        }
    }
}

// ---------------- per-node edge softmax, 2-pass: store unnormalized exp + 1/s ----------------
template <int H>
__global__ void edge_softmax_kernel(const int* __restrict__ offs, const int* __restrict__ csr,
                                    const float* __restrict__ als, const float* __restrict__ ald,
                                    float* __restrict__ lg, float* __restrict__ invs, int Nn) {
    int wid = threadIdx.x >> 6, lane = threadIdx.x & 63;
    int n = blockIdx.x * 4 + wid;
    if (n >= Nn) return;
    int b = offs[n], e = offs[n + 1];
    float aldn[H];
    #pragma unroll
    for (int h = 0; h < H; ++h) aldn[h] = ald[n * H + h];
    float mx[H];
    #pragma unroll
    for (int h = 0; h < H; ++h) mx[h] = -1e30f;
    for (int p = b + lane; p < e; p += 64) {
        int s = csr[p];
        #pragma unroll
        for (int h = 0; h < H; ++h) {
            float l = als[s * H + h] + aldn[h];
            l = (l > 0.f) ? l : NEG_SLOPE * l;
            lg[p * H + h] = l;
            mx[h] = fmaxf(mx[h], l);
        }
    }
    #pragma unroll
    for (int h = 0; h < H; ++h) mx[h] = wred_max(mx[h]);
    float sm[H];
    #pragma unroll
    for (int h = 0; h < H; ++h) sm[h] = 0.f;
    for (int p = b + lane; p < e; p += 64) {
        #pragma unroll
        for (int h = 0; h < H; ++h) {
            float t = expf(lg[p * H + h] - mx[h]);
            lg[p * H + h] = t;
            sm[h] += t;
        }
    }
    #pragma unroll
    for (int h = 0; h < H; ++h) sm[h] = wred_sum(sm[h]);
    if (lane == 0) {
        #pragma unroll
        for (int h = 0; h < H; ++h) invs[n * H + h] = 1.f / (sm[h] + 1e-16f);
    }
}

// ---------------- layer-1 aggregation (wave/node, float4, 2 edges/iter) + bias+BN+ReLU ----------------
__global__ __launch_bounds__(256) void agg1_kernel(const int* __restrict__ offs, const int* __restrict__ csr,
                            const float* __restrict__ h1, const float* __restrict__ ex,
                            const float* __restrict__ invs,
                            const float* __restrict__ b1, const float* __restrict__ gam,
                            const float* __restrict__ bet, const float* __restrict__ mean,
                            const float* __restrict__ var, float* __restrict__ hbn, int Nn) {
    int wid = threadIdx.x >> 6, lane = threadIdx.x & 63;
    int n = blockIdx.x * 4 + wid;
    if (n >= Nn) return;
    int sub = lane >> 5, l32 = lane & 31;
    int head = l32 >> 4;
    int b = offs[n], e = offs[n + 1];
    float4 acc = {0.f, 0.f, 0.f, 0.f};
    for (int p = b + sub; p < e; p += 2) {
        int s = csr[p];
        float a = ex[p * 2 + head];
        float4 v = *(const float4*)(h1 + (size_t)s * 128 + 4 * l32);
        acc.x += v.x * a; acc.y += v.y * a; acc.z += v.z * a; acc.w += v.w * a;
    }
    acc.x += __shfl_xor(acc.x, 32);
    acc.y += __shfl_xor(acc.y, 32);
    acc.z += __shfl_xor(acc.z, 32);
    acc.w += __shfl_xor(acc.w, 32);
    if (sub == 0) {
        float inv = invs[n * 2 + head];
        int c = 4 * l32;
        float4 bb = *(const float4*)(b1 + c);
        float4 gg = *(const float4*)(gam + c);
        float4 be = *(const float4*)(bet + c);
        float4 mm = *(const float4*)(mean + c);
        float4 vv = *(const float4*)(var + c);
        float4 o;
        o.x = fmaxf((acc.x * inv + bb.x - mm.x) * rsqrtf(vv.x + BN_EPS) * gg.x + be.x, 0.f);
        o.y = fmaxf((acc.y * inv + bb.y - mm.y) * rsqrtf(vv.y + BN_EPS) * gg.y + be.y, 0.f);
        o.z = fmaxf((acc.z * inv + bb.z - mm.z) * rsqrtf(vv.z + BN_EPS) * gg.z + be.z, 0.f);
        o.w = fmaxf((acc.w * inv + bb.w - mm.w) * rsqrtf(vv.w + BN_EPS) * gg.w + be.w, 0.f);
        *(float4*)(hbn + (size_t)n * 128 + c) = o;
    }
}

// ---------------- layer 2 GEMM tiled + fused al2 ----------------
__global__ __launch_bounds__(256) void gemm2_tiled(const float* __restrict__ hbn,
                                                   const float* __restrict__ W2,
                                                   const float* __restrict__ a2s,
                                                   const float* __restrict__ a2d,
                                                   float* __restrict__ h2p,
                                                   float* __restrict__ als, float* __restrict__ ald,
                                                   int Nn) {
    __shared__ float As[64][33];
    __shared__ float Bs[128][68];
    __shared__ float redS[64][17];
    __shared__ float redD[64][17];
    int t  = threadIdx.x;
    int tx = t & 15;
    int ty = t >> 4;
    int br = blockIdx.x * 64;

    #pragma unroll
    for (int i = 0; i < 8; ++i) {
        int f  = t + 256 * i;
        int kk = f >> 4, c4 = f & 15;
        float4 v = {0.f, 0.f, 0.f, 0.f};
        if (c4 < 10) v = *(const float4*)(W2 + (size_t)kk * 40 + 4 * c4);
        *(float4*)&Bs[kk][4 * c4] = v;
    }
    float as4[4], ad4[4];
    #pragma unroll
    for (int j = 0; j < 4; ++j) {
        int c = 4 * tx + j;
        as4[j] = (c < 40) ? a2s[c] : 0.f;
        ad4[j] = (c < 40) ? a2d[c] : 0.f;
    }

    float acc[4][4];
    #pragma unroll
    for (int i = 0; i < 4; ++i)
        #pragma unroll
        for (int j = 0; j < 4; ++j) acc[i][j] = 0.f;

    int k4  = t & 7;
    int rowA = t >> 3;
    __syncthreads();

    for (int k0 = 0; k0 < 128; k0 += 32) {
        #pragma unroll
        for (int i = 0; i < 2; ++i) {
            int r  = rowA + 32 * i;
            int gr = min(br + r, Nn - 1);
            float4 v = *(const float4*)(hbn + (size_t)gr * 128 + k0 + 4 * k4);
            As[r][4 * k4 + 0] = v.x; As[r][4 * k4 + 1] = v.y;
            As[r][4 * k4 + 2] = v.z; As[r][4 * k4 + 3] = v.w;
        }
        __syncthreads();
        #pragma unroll
        for (int kk = 0; kk < 32; ++kk) {
            float4 b0 = *(const float4*)&Bs[k0 + kk][4 * tx];
            #pragma unroll
            for (int i = 0; i < 4; ++i) {
                float a = As[4 * ty + i][kk];
                acc[i][0] += a * b0.x; acc[i][1] += a * b0.y;
                acc[i][2] += a * b0.z; acc[i][3] += a * b0.w;
            }
        }
        __syncthreads();
    }
    #pragma unroll
    for (int i = 0; i < 4; ++i) {
        redS[4 * ty + i][tx] = acc[i][0] * as4[0] + acc[i][1] * as4[1] + acc[i][2] * as4[2] + acc[i][3] * as4[3];
        redD[4 * ty + i][tx] = acc[i][0] * ad4[0] + acc[i][1] * ad4[1] + acc[i][2] * ad4[2] + acc[i][3] * ad4[3];
        int r = br + 4 * ty + i;
        if (r < Nn) {
            float4 o = {acc[i][0], acc[i][1], acc[i][2], acc[i][3]};
            *(float4*)(h2p + (size_t)r * 64 + 4 * tx) = o;
        }
    }
    __syncthreads();
    if (t < 64) {
        int r = br + t;
        if (r < Nn) {
            float sS = 0.f, sD = 0.f;
            #pragma unroll
            for (int xx = 0; xx < 16; ++xx) { sS += redS[t][xx]; sD += redD[t][xx]; }
            als[r] = sS; ald[r] = sD;
        }
    }
}

// ---------------- layer-2 aggregation + bias + log_softmax ----------------
__global__ __launch_bounds__(256) void agg2_kernel(const int* __restrict__ offs, const int* __restrict__ csr,
                            const float* __restrict__ h2p, const float* __restrict__ ex,
                            const float* __restrict__ invs, const float* __restrict__ b2,
                            float* __restrict__ out, int Nn) {
    int wid = threadIdx.x >> 6, lane = threadIdx.x & 63;
    int n = blockIdx.x * 4 + wid;
    if (n >= Nn) return;
    int sub = lane >> 5, l32 = lane & 31;
    int b = offs[n], e = offs[n + 1];
    float2 acc = {0.f, 0.f};
    for (int p = b + sub; p < e; p += 2) {
        int s = csr[p];
        float a = ex[p];
        float2 v = *(const float2*)(h2p + (size_t)s * 64 + 2 * l32);
        acc.x += v.x * a; acc.y += v.y * a;
    }
    acc.x += __shfl_xor(acc.x, 32);
    acc.y += __shfl_xor(acc.y, 32);
    float inv = invs[n];
    bool valid = (sub == 0) && (l32 < 20);
    float v0 = -1e30f, v1 = -1e30f;
    if (valid) {
        v0 = acc.x * inv + b2[2 * l32];
        v1 = acc.y * inv + b2[2 * l32 + 1];
    }
    float m = wred_max(fmaxf(v0, v1));
    float es = valid ? (expf(v0 - m) + expf(v1 - m)) : 0.f;
    float ssum = wred_sum(es);
    float lse = m + logf(ssum);
    if (valid) {
        float2 o = {v0 - lse, v1 - lse};
        *(float2*)(out + (size_t)n * 40 + 2 * l32) = o;
    }
}

extern "C" void kernel_launch(void* const* d_in, const int* in_sizes, int n_in,
                              void* d_out, int out_size, void* d_ws, size_t ws_size,
                              hipStream_t stream) {
    const float* x    = (const float*)d_in[0];
    const int*   ei   = (const int*)d_in[1];
    const float* W1   = (const float*)d_in[2];
    const float* a1s  = (const float*)d_in[3];
    const float* a1d  = (const float*)d_in[4];
    const float* b1   = (const float*)d_in[5];
    const float* g1   = (const float*)d_in[6];
    const float* be1  = (const float*)d_in[7];
    const float* mn1  = (const float*)d_in[8];
    const float* vr1  = (const float*)d_in[9];
    const float* W2   = (const float*)d_in[10];
    const float* a2s  = (const float*)d_in[11];
    const float* a2d  = (const float*)d_in[12];
    const float* b2   = (const float*)d_in[13];
    float* out = (float*)d_out;

    const int N  = in_sizes[0] / 128;
    const int E  = in_sizes[1] / 2;
    const int Et = E + N;
    const int nScanB = (N + SCAN_CHUNK - 1) / SCAN_CHUNK;

    char* p = (char*)d_ws;
    auto alloc = [&](size_t bytes) -> void* {
        void* r = (void*)p;
        p += (bytes + 255) & ~(size_t)255;
        return r;
    };
    int*   deg   = (int*)alloc((size_t)N * 4);
    int*   offs  = (int*)alloc((size_t)(N + 1) * 4);
    int*   cur   = (int*)alloc((size_t)N * 4);
    int*   bsum  = (int*)alloc((size_t)(nScanB + 1) * 4);
    int*   bpre  = (int*)alloc((size_t)(nScanB + 1) * 4);
    int*   csr   = (int*)alloc((size_t)Et * 4);
    float* h1    = (float*)alloc((size_t)N * 128 * 4);
    float* al1sv = (float*)alloc((size_t)N * 2 * 4);
    float* al1dv = (float*)alloc((size_t)N * 2 * 4);
    float* ex1   = (float*)alloc((size_t)Et * 2 * 4);
    float* inv1  = (float*)alloc((size_t)N * 2 * 4);
    float* hbn   = (float*)alloc((size_t)N * 128 * 4);
    float* h2p   = (float*)alloc((size_t)N * 64 * 4);
    float* al2sv = (float*)alloc((size_t)N * 4);
    float* al2dv = (float*)alloc((size_t)N * 4);
    float* ex2   = (float*)alloc((size_t)Et * 4);
    float* inv2  = (float*)alloc((size_t)N * 4);
    (void)ws_size;

    hipMemsetAsync(deg, 0, (size_t)N * 4, stream);

    int tpb = 256;
    hist_kernel<<<(Et + tpb - 1) / tpb, tpb, 0, stream>>>(ei, E, Et, deg);
    scan_blocksum<<<nScanB, 256, 0, stream>>>(deg, bsum, N);
    scan_bsums<<<1, 1024, 0, stream>>>(bsum, bpre, nScanB);
    scan_scatter<<<nScanB, 256, 0, stream>>>(deg, bpre, offs, cur, N, nScanB);
    scatter_kernel<<<(Et + tpb - 1) / tpb, tpb, 0, stream>>>(ei, E, Et, cur, csr);

    gemm1_tiled<<<(N + 63) / 64, 256, 0, stream>>>(x, W1, a1s, a1d, h1, al1sv, al1dv, N);
    edge_softmax_kernel<2><<<(N + 3) / 4, 256, 0, stream>>>(offs, csr, al1sv, al1dv, ex1, inv1, N);
    agg1_kernel<<<(N + 3) / 4, 256, 0, stream>>>(offs, csr, h1, ex1, inv1, b1, g1, be1, mn1, vr1, hbn, N);

    gemm2_tiled<<<(N + 63) / 64, 256, 0, stream>>>(hbn, W2, a2s, a2d, h2p, al2sv, al2dv, N);
    edge_softmax_kernel<1><<<(N + 3) / 4, 256, 0, stream>>>(offs, csr, al2sv, al2dv, ex2, inv2, N);
    agg2_kernel<<<(N + 3) / 4, 256, 0, stream>>>(offs, csr, h2p, ex2, inv2, b2, out, N);
}

// Round 4
// 370.832 us; speedup vs baseline: 1.7096x; 1.0725x over previous
//
#include <hip/hip_runtime.h>
#include <hip/hip_bf16.h>

#define NEG_SLOPE 0.2f
#define BN_EPS 1e-5f

__device__ __forceinline__ float wred_sum(float v) {
    #pragma unroll
    for (int m = 32; m > 0; m >>= 1) v += __shfl_xor(v, m);
    return v;
}
__device__ __forceinline__ float wred_max(float v) {
    #pragma unroll
    for (int m = 32; m > 0; m >>= 1) v = fmaxf(v, __shfl_xor(v, m));
    return v;
}

__device__ __forceinline__ unsigned pack_bf16(float a, float b) {
    __hip_bfloat162 t;
    t.x = __float2bfloat16(a);
    t.y = __float2bfloat16(b);
    return *(unsigned*)&t;
}
__device__ __forceinline__ float2 unpack_bf16(unsigned u) {
    __hip_bfloat162 t = *(__hip_bfloat162*)&u;
    return {__bfloat162float(t.x), __bfloat162float(t.y)};
}

// ---------------- CSR build ----------------
__global__ void hist_kernel(const int* __restrict__ ei, int E, int Et, int* __restrict__ deg) {
    int idx = blockIdx.x * blockDim.x + threadIdx.x;
    if (idx >= Et) return;
    int d = (idx < E) ? ei[E + idx] : (idx - E);
    atomicAdd(&deg[d], 1);
}

#define SCAN_CHUNK 2048

__global__ __launch_bounds__(256) void scan_blocksum(const int* __restrict__ deg,
                                                     int* __restrict__ bsum, int n) {
    __shared__ int red[256];
    int b = blockIdx.x, t = threadIdx.x;
    int base = b * SCAN_CHUNK + t * 8;
    int s = 0;
    #pragma unroll
    for (int i = 0; i < 8; ++i) { int idx = base + i; if (idx < n) s += deg[idx]; }
    red[t] = s;
    __syncthreads();
    for (int off = 128; off > 0; off >>= 1) {
        if (t < off) red[t] += red[t + off];
        __syncthreads();
    }
    if (t == 0) bsum[b] = red[0];
}

__global__ __launch_bounds__(1024) void scan_bsums(const int* __restrict__ bsum,
                                                   int* __restrict__ bpre, int nb) {
    __shared__ int s[1024];
    int t = threadIdx.x;
    int v = (t < nb) ? bsum[t] : 0;
    s[t] = v;
    __syncthreads();
    for (int off = 1; off < 1024; off <<= 1) {
        int u = (t >= off) ? s[t - off] : 0;
        __syncthreads();
        s[t] += u;
        __syncthreads();
    }
    if (t < nb) bpre[t] = s[t] - v;
    if (t == 1023) bpre[nb] = s[1023];
}

__global__ __launch_bounds__(256) void scan_scatter(const int* __restrict__ deg,
                                                    const int* __restrict__ bpre,
                                                    int* __restrict__ offs, int* __restrict__ cur,
                                                    int n, int nb) {
    __shared__ int red[256];
    int b = blockIdx.x, t = threadIdx.x;
    int base = b * SCAN_CHUNK + t * 8;
    int loc[8];
    int s = 0;
    #pragma unroll
    for (int i = 0; i < 8; ++i) {
        int idx = base + i;
        int d = (idx < n) ? deg[idx] : 0;
        loc[i] = s;
        s += d;
    }
    red[t] = s;
    __syncthreads();
    int v = s;
    for (int off = 1; off < 256; off <<= 1) {
        int u = (t >= off) ? red[t - off] : 0;
        __syncthreads();
        red[t] += u;
        __syncthreads();
    }
    int tpre = red[t] - v + bpre[b];
    #pragma unroll
    for (int i = 0; i < 8; ++i) {
        int idx = base + i;
        if (idx < n) {
            int o = tpre + loc[i];
            offs[idx] = o;
            cur[idx]  = o;
        }
    }
    if (b == 0 && t == 0) offs[n] = bpre[nb];
}

__global__ void scatter_kernel(const int* __restrict__ ei, int E, int Et,
                               int* __restrict__ cur, int* __restrict__ csr_src) {
    int idx = blockIdx.x * blockDim.x + threadIdx.x;
    if (idx >= Et) return;
    int s, d;
    if (idx < E) { s = ei[idx]; d = ei[E + idx]; }
    else         { s = idx - E; d = idx - E; }
    int pos = atomicAdd(&cur[d], 1);
    csr_src[pos] = s;
}

// ---------------- Layer 1 GEMM + fused al1, bf16-packed output ----------------
__global__ __launch_bounds__(256) void gemm1_tiled(const float* __restrict__ x,
                                                   const float* __restrict__ W,
                                                   const float* __restrict__ a1s,
                                                   const float* __restrict__ a1d,
                                                   unsigned* __restrict__ h1b,
                                                   float* __restrict__ als,
                                                   float* __restrict__ ald, int Nn) {
    __shared__ float As[64][33];
    __shared__ float Bs[32][132];
    __shared__ float4 red4[64][17];
    int t  = threadIdx.x;
    int tx = t & 15;
    int ty = t >> 4;
    int br = blockIdx.x * 64;

    float acc[4][8];
    #pragma unroll
    for (int i = 0; i < 4; ++i)
        #pragma unroll
        for (int j = 0; j < 8; ++j) acc[i][j] = 0.f;

    int k4  = t & 7;
    int rowA = t >> 3;

    for (int k0 = 0; k0 < 128; k0 += 32) {
        #pragma unroll
        for (int i = 0; i < 2; ++i) {
            int r  = rowA + 32 * i;
            int gr = min(br + r, Nn - 1);
            float4 v = *(const float4*)(x + (size_t)gr * 128 + k0 + 4 * k4);
            As[r][4 * k4 + 0] = v.x; As[r][4 * k4 + 1] = v.y;
            As[r][4 * k4 + 2] = v.z; As[r][4 * k4 + 3] = v.w;
        }
        #pragma unroll
        for (int i = 0; i < 4; ++i) {
            int f  = t + 256 * i;
            int kk = f >> 5, c4 = f & 31;
            *(float4*)&Bs[kk][4 * c4] = *(const float4*)(W + (size_t)(k0 + kk) * 128 + 4 * c4);
        }
        __syncthreads();
        #pragma unroll
        for (int kk = 0; kk < 32; ++kk) {
            float4 b0 = *(const float4*)&Bs[kk][4 * tx];
            float4 b1 = *(const float4*)&Bs[kk][64 + 4 * tx];
            #pragma unroll
            for (int i = 0; i < 4; ++i) {
                float a = As[4 * ty + i][kk];
                acc[i][0] += a * b0.x; acc[i][1] += a * b0.y;
                acc[i][2] += a * b0.z; acc[i][3] += a * b0.w;
                acc[i][4] += a * b1.x; acc[i][5] += a * b1.y;
                acc[i][6] += a * b1.z; acc[i][7] += a * b1.w;
            }
        }
        __syncthreads();
    }
    float s_lo[4], s_hi[4], d_lo[4], d_hi[4];
    #pragma unroll
    for (int j = 0; j < 4; ++j) {
        s_lo[j] = a1s[4 * tx + j];      s_hi[j] = a1s[64 + 4 * tx + j];
        d_lo[j] = a1d[4 * tx + j];      d_hi[j] = a1d[64 + 4 * tx + j];
    }
    #pragma unroll
    for (int i = 0; i < 4; ++i) {
        float4 pp = {0.f, 0.f, 0.f, 0.f};
        #pragma unroll
        for (int j = 0; j < 4; ++j) {
            pp.x += acc[i][j] * s_lo[j];
            pp.y += acc[i][4 + j] * s_hi[j];
            pp.z += acc[i][j] * d_lo[j];
            pp.w += acc[i][4 + j] * d_hi[j];
        }
        red4[4 * ty + i][tx] = pp;
        int r = br + 4 * ty + i;
        if (r < Nn) {
            uint2 lo = {pack_bf16(acc[i][0], acc[i][1]), pack_bf16(acc[i][2], acc[i][3])};
            uint2 hi = {pack_bf16(acc[i][4], acc[i][5]), pack_bf16(acc[i][6], acc[i][7])};
            *(uint2*)(h1b + (size_t)r * 64 + 2 * tx)      = lo;
            *(uint2*)(h1b + (size_t)r * 64 + 32 + 2 * tx) = hi;
        }
    }
    __syncthreads();
    if (t < 64) {
        int r = br + t;
        if (r < Nn) {
            float4 s = {0.f, 0.f, 0.f, 0.f};
            #pragma unroll
            for (int xx = 0; xx < 16; ++xx) {
                float4 p = red4[t][xx];
                s.x += p.x; s.y += p.y; s.z += p.z; s.w += p.w;
            }
            als[r * 2] = s.x; als[r * 2 + 1] = s.y;
            ald[r * 2] = s.z; ald[r * 2 + 1] = s.w;
        }
    }
}

// ---------------- per-node edge softmax, 2-pass: store unnormalized exp + 1/s ----------------
template <int H>
__global__ void edge_softmax_kernel(const int* __restrict__ offs, const int* __restrict__ csr,
                                    const float* __restrict__ als, const float* __restrict__ ald,
                                    float* __restrict__ lg, float* __restrict__ invs, int Nn) {
    int wid = threadIdx.x >> 6, lane = threadIdx.x & 63;
    int n = blockIdx.x * 4 + wid;
    if (n >= Nn) return;
    int b = offs[n], e = offs[n + 1];
    float aldn[H];
    #pragma unroll
    for (int h = 0; h < H; ++h) aldn[h] = ald[n * H + h];
    float mx[H];
    #pragma unroll
    for (int h = 0; h < H; ++h) mx[h] = -1e30f;
    for (int p = b + lane; p < e; p += 64) {
        int s = csr[p];
        #pragma unroll
        for (int h = 0; h < H; ++h) {
            float l = als[s * H + h] + aldn[h];
            l = (l > 0.f) ? l : NEG_SLOPE * l;
            lg[p * H + h] = l;
            mx[h] = fmaxf(mx[h], l);
        }
    }
    #pragma unroll
    for (int h = 0; h < H; ++h) mx[h] = wred_max(mx[h]);
    float sm[H];
    #pragma unroll
    for (int h = 0; h < H; ++h) sm[h] = 0.f;
    for (int p = b + lane; p < e; p += 64) {
        #pragma unroll
        for (int h = 0; h < H; ++h) {
            float t = expf(lg[p * H + h] - mx[h]);
            lg[p * H + h] = t;
            sm[h] += t;
        }
    }
    #pragma unroll
    for (int h = 0; h < H; ++h) sm[h] = wred_sum(sm[h]);
    if (lane == 0) {
        #pragma unroll
        for (int h = 0; h < H; ++h) invs[n * H + h] = 1.f / (sm[h] + 1e-16f);
    }
}

// ---------------- layer-1 aggregation: bf16 gather, 4 edges in flight ----------------
__global__ __launch_bounds__(256) void agg1_kernel(const int* __restrict__ offs, const int* __restrict__ csr,
                            const unsigned* __restrict__ h1b, const float* __restrict__ ex,
                            const float* __restrict__ invs,
                            const float* __restrict__ b1, const float* __restrict__ gam,
                            const float* __restrict__ bet, const float* __restrict__ mean,
                            const float* __restrict__ var, float* __restrict__ hbn, int Nn) {
    int wid = threadIdx.x >> 6, lane = threadIdx.x & 63;
    int n = blockIdx.x * 4 + wid;
    if (n >= Nn) return;
    int sub = lane >> 4;       // 0..3: edge slot
    int l16 = lane & 15;       // covers cols 8*l16 .. 8*l16+7
    int head = l16 >> 3;
    int b = offs[n], e = offs[n + 1];
    float acc[8];
    #pragma unroll
    for (int j = 0; j < 8; ++j) acc[j] = 0.f;
    for (int p = b + sub; p < e; p += 4) {
        int s = csr[p];
        float a = ex[p * 2 + head];
        uint4 v = *(const uint4*)(h1b + (size_t)s * 64 + 4 * l16);
        float2 f0 = unpack_bf16(v.x), f1 = unpack_bf16(v.y);
        float2 f2 = unpack_bf16(v.z), f3 = unpack_bf16(v.w);
        acc[0] += f0.x * a; acc[1] += f0.y * a;
        acc[2] += f1.x * a; acc[3] += f1.y * a;
        acc[4] += f2.x * a; acc[5] += f2.y * a;
        acc[6] += f3.x * a; acc[7] += f3.y * a;
    }
    #pragma unroll
    for (int j = 0; j < 8; ++j) {
        acc[j] += __shfl_xor(acc[j], 16);
        acc[j] += __shfl_xor(acc[j], 32);
    }
    if (sub == 0) {
        float inv = invs[n * 2 + head];
        int c = 8 * l16;
        #pragma unroll
        for (int half = 0; half < 2; ++half) {
            int cc = c + 4 * half;
            float4 bb = *(const float4*)(b1 + cc);
            float4 gg = *(const float4*)(gam + cc);
            float4 be = *(const float4*)(bet + cc);
            float4 mm = *(const float4*)(mean + cc);
            float4 vv = *(const float4*)(var + cc);
            float4 o;
            o.x = fmaxf((acc[4*half+0] * inv + bb.x - mm.x) * rsqrtf(vv.x + BN_EPS) * gg.x + be.x, 0.f);
            o.y = fmaxf((acc[4*half+1] * inv + bb.y - mm.y) * rsqrtf(vv.y + BN_EPS) * gg.y + be.y, 0.f);
            o.z = fmaxf((acc[4*half+2] * inv + bb.z - mm.z) * rsqrtf(vv.z + BN_EPS) * gg.z + be.z, 0.f);
            o.w = fmaxf((acc[4*half+3] * inv + bb.w - mm.w) * rsqrtf(vv.w + BN_EPS) * gg.w + be.w, 0.f);
            *(float4*)(hbn + (size_t)n * 128 + cc) = o;
        }
    }
}

// ---------------- layer 2 GEMM tiled + fused al2, bf16-packed output ----------------
__global__ __launch_bounds__(256) void gemm2_tiled(const float* __restrict__ hbn,
                                                   const float* __restrict__ W2,
                                                   const float* __restrict__ a2s,
                                                   const float* __restrict__ a2d,
                                                   unsigned* __restrict__ h2b,
                                                   float* __restrict__ als, float* __restrict__ ald,
                                                   int Nn) {
    __shared__ float As[64][33];
    __shared__ float Bs[128][68];
    __shared__ float redS[64][17];
    __shared__ float redD[64][17];
    int t  = threadIdx.x;
    int tx = t & 15;
    int ty = t >> 4;
    int br = blockIdx.x * 64;

    #pragma unroll
    for (int i = 0; i < 8; ++i) {
        int f  = t + 256 * i;
        int kk = f >> 4, c4 = f & 15;
        float4 v = {0.f, 0.f, 0.f, 0.f};
        if (c4 < 10) v = *(const float4*)(W2 + (size_t)kk * 40 + 4 * c4);
        *(float4*)&Bs[kk][4 * c4] = v;
    }
    float as4[4], ad4[4];
    #pragma unroll
    for (int j = 0; j < 4; ++j) {
        int c = 4 * tx + j;
        as4[j] = (c < 40) ? a2s[c] : 0.f;
        ad4[j] = (c < 40) ? a2d[c] : 0.f;
    }

    float acc[4][4];
    #pragma unroll
    for (int i = 0; i < 4; ++i)
        #pragma unroll
        for (int j = 0; j < 4; ++j) acc[i][j] = 0.f;

    int k4  = t & 7;
    int rowA = t >> 3;
    __syncthreads();

    for (int k0 = 0; k0 < 128; k0 += 32) {
        #pragma unroll
        for (int i = 0; i < 2; ++i) {
            int r  = rowA + 32 * i;
            int gr = min(br + r, Nn - 1);
            float4 v = *(const float4*)(hbn + (size_t)gr * 128 + k0 + 4 * k4);
            As[r][4 * k4 + 0] = v.x; As[r][4 * k4 + 1] = v.y;
            As[r][4 * k4 + 2] = v.z; As[r][4 * k4 + 3] = v.w;
        }
        __syncthreads();
        #pragma unroll
        for (int kk = 0; kk < 32; ++kk) {
            float4 b0 = *(const float4*)&Bs[k0 + kk][4 * tx];
            #pragma unroll
            for (int i = 0; i < 4; ++i) {
                float a = As[4 * ty + i][kk];
                acc[i][0] += a * b0.x; acc[i][1] += a * b0.y;
                acc[i][2] += a * b0.z; acc[i][3] += a * b0.w;
            }
        }
        __syncthreads();
    }
    #pragma unroll
    for (int i = 0; i < 4; ++i) {
        redS[4 * ty + i][tx] = acc[i][0] * as4[0] + acc[i][1] * as4[1] + acc[i][2] * as4[2] + acc[i][3] * as4[3];
        redD[4 * ty + i][tx] = acc[i][0] * ad4[0] + acc[i][1] * ad4[1] + acc[i][2] * ad4[2] + acc[i][3] * ad4[3];
        int r = br + 4 * ty + i;
        if (r < Nn) {
            uint2 pk = {pack_bf16(acc[i][0], acc[i][1]), pack_bf16(acc[i][2], acc[i][3])};
            *(uint2*)(h2b + (size_t)r * 32 + 2 * tx) = pk;
        }
    }
    __syncthreads();
    if (t < 64) {
        int r = br + t;
        if (r < Nn) {
            float sS = 0.f, sD = 0.f;
            #pragma unroll
            for (int xx = 0; xx < 16; ++xx) { sS += redS[t][xx]; sD += redD[t][xx]; }
            als[r] = sS; ald[r] = sD;
        }
    }
}

// ---------------- layer-2 aggregation: bf16 gather, 4 edges in flight, + log_softmax ----------------
__global__ __launch_bounds__(256) void agg2_kernel(const int* __restrict__ offs, const int* __restrict__ csr,
                            const unsigned* __restrict__ h2b, const float* __restrict__ ex,
                            const float* __restrict__ invs, const float* __restrict__ b2,
                            float* __restrict__ out, int Nn) {
    int wid = threadIdx.x >> 6, lane = threadIdx.x & 63;
    int n = blockIdx.x * 4 + wid;
    if (n >= Nn) return;
    int sub = lane >> 4;       // 0..3
    int l16 = lane & 15;       // cols 4*l16 .. 4*l16+3 (valid l16 < 10)
    int b = offs[n], e = offs[n + 1];
    float acc[4];
    #pragma unroll
    for (int j = 0; j < 4; ++j) acc[j] = 0.f;
    for (int p = b + sub; p < e; p += 4) {
        int s = csr[p];
        float a = ex[p];
        uint2 v = *(const uint2*)(h2b + (size_t)s * 32 + 2 * l16);
        float2 f0 = unpack_bf16(v.x), f1 = unpack_bf16(v.y);
        acc[0] += f0.x * a; acc[1] += f0.y * a;
        acc[2] += f1.x * a; acc[3] += f1.y * a;
    }
    #pragma unroll
    for (int j = 0; j < 4; ++j) {
        acc[j] += __shfl_xor(acc[j], 16);
        acc[j] += __shfl_xor(acc[j], 32);
    }
    float inv = invs[n];
    bool valid = (l16 < 10);
    float v0 = -1e30f, v1 = -1e30f, v2 = -1e30f, v3 = -1e30f;
    if (valid) {
        int c = 4 * l16;
        v0 = acc[0] * inv + b2[c];
        v1 = acc[1] * inv + b2[c + 1];
        v2 = acc[2] * inv + b2[c + 2];
        v3 = acc[3] * inv + b2[c + 3];
    }
    float m = wred_max(fmaxf(fmaxf(v0, v1), fmaxf(v2, v3)));
    float es = (valid && sub == 0)
             ? (expf(v0 - m) + expf(v1 - m) + expf(v2 - m) + expf(v3 - m)) : 0.f;
    float ssum = wred_sum(es);
    float lse = m + logf(ssum);
    if (sub == 0 && valid) {
        float4 o = {v0 - lse, v1 - lse, v2 - lse, v3 - lse};
        *(float4*)(out + (size_t)n * 40 + 4 * l16) = o;
    }
}

extern "C" void kernel_launch(void* const* d_in, const int* in_sizes, int n_in,
                              void* d_out, int out_size, void* d_ws, size_t ws_size,
                              hipStream_t stream) {
    const float* x    = (const float*)d_in[0];
    const int*   ei   = (const int*)d_in[1];
    const float* W1   = (const float*)d_in[2];
    const float* a1s  = (const float*)d_in[3];
    const float* a1d  = (const float*)d_in[4];
    const float* b1   = (const float*)d_in[5];
    const float* g1   = (const float*)d_in[6];
    const float* be1  = (const float*)d_in[7];
    const float* mn1  = (const float*)d_in[8];
    const float* vr1  = (const float*)d_in[9];
    const float* W2   = (const float*)d_in[10];
    const float* a2s  = (const float*)d_in[11];
    const float* a2d  = (const float*)d_in[12];
    const float* b2   = (const float*)d_in[13];
    float* out = (float*)d_out;

    const int N  = in_sizes[0] / 128;
    const int E  = in_sizes[1] / 2;
    const int Et = E + N;
    const int nScanB = (N + SCAN_CHUNK - 1) / SCAN_CHUNK;

    char* p = (char*)d_ws;
    auto alloc = [&](size_t bytes) -> void* {
        void* r = (void*)p;
        p += (bytes + 255) & ~(size_t)255;
        return r;
    };
    int*      deg   = (int*)alloc((size_t)N * 4);
    int*      offs  = (int*)alloc((size_t)(N + 1) * 4);
    int*      cur   = (int*)alloc((size_t)N * 4);
    int*      bsum  = (int*)alloc((size_t)(nScanB + 1) * 4);
    int*      bpre  = (int*)alloc((size_t)(nScanB + 1) * 4);
    int*      csr   = (int*)alloc((size_t)Et * 4);
    unsigned* h1b   = (unsigned*)alloc((size_t)N * 64 * 4);
    float*    al1sv = (float*)alloc((size_t)N * 2 * 4);
    float*    al1dv = (float*)alloc((size_t)N * 2 * 4);
    float*    ex1   = (float*)alloc((size_t)Et * 2 * 4);
    float*    inv1  = (float*)alloc((size_t)N * 2 * 4);
    float*    hbn   = (float*)alloc((size_t)N * 128 * 4);
    unsigned* h2b   = (unsigned*)alloc((size_t)N * 32 * 4);
    float*    al2sv = (float*)alloc((size_t)N * 4);
    float*    al2dv = (float*)alloc((size_t)N * 4);
    float*    ex2   = (float*)alloc((size_t)Et * 4);
    float*    inv2  = (float*)alloc((size_t)N * 4);
    (void)ws_size;

    hipMemsetAsync(deg, 0, (size_t)N * 4, stream);

    int tpb = 256;
    hist_kernel<<<(Et + tpb - 1) / tpb, tpb, 0, stream>>>(ei, E, Et, deg);
    scan_blocksum<<<nScanB, 256, 0, stream>>>(deg, bsum, N);
    scan_bsums<<<1, 1024, 0, stream>>>(bsum, bpre, nScanB);
    scan_scatter<<<nScanB, 256, 0, stream>>>(deg, bpre, offs, cur, N, nScanB);
    scatter_kernel<<<(Et + tpb - 1) / tpb, tpb, 0, stream>>>(ei, E, Et, cur, csr);

    gemm1_tiled<<<(N + 63) / 64, 256, 0, stream>>>(x, W1, a1s, a1d, h1b, al1sv, al1dv, N);
    edge_softmax_kernel<2><<<(N + 3) / 4, 256, 0, stream>>>(offs, csr, al1sv, al1dv, ex1, inv1, N);
    agg1_kernel<<<(N + 3) / 4, 256, 0, stream>>>(offs, csr, h1b, ex1, inv1, b1, g1, be1, mn1, vr1, hbn, N);

    gemm2_tiled<<<(N + 63) / 64, 256, 0, stream>>>(hbn, W2, a2s, a2d, h2b, al2sv, al2dv, N);
    edge_softmax_kernel<1><<<(N + 3) / 4, 256, 0, stream>>>(offs, csr, al2sv, al2dv, ex2, inv2, N);
    agg2_kernel<<<(N + 3) / 4, 256, 0, stream>>>(offs, csr, h2b, ex2, inv2, b2, out, N);
}